// Round 6
// baseline (5805.233 us; speedup 1.0000x reference)
//
#include <hip/hip_runtime.h>
#include <hip/hip_cooperative_groups.h>
#include <math.h>

namespace cg = cooperative_groups;

#define BB 64
#define TT 512
#define FF 512
#define HH 1024
#define NG 4096  // 4H

typedef _Float16 half8 __attribute__((ext_vector_type(8)));
typedef float f32x4 __attribute__((ext_vector_type(4)));
typedef unsigned long long u64;

__device__ __forceinline__ float sigm(float x) { return 1.0f / (1.0f + __expf(-x)); }
__device__ __forceinline__ float tanh_fast(float x) {
    x = fminf(fmaxf(x, -30.0f), 30.0f);
    float e = __expf(2.0f * x);
    return (e - 1.0f) / (e + 1.0f);
}

// ---------------------------------------------------------------------------
// x fp32 -> f16, same [B,T,F] layout. 32 MiB into ws.
// ---------------------------------------------------------------------------
__global__ __launch_bounds__(256) void cvt_x(const float* __restrict__ x,
                                             _Float16* __restrict__ x16)
{
    size_t i = ((size_t)blockIdx.x * 256 + threadIdx.x) * 8;
    float4 a = *(const float4*)(x + i);
    float4 b = *(const float4*)(x + i + 4);
    half8 v;
    v[0] = (_Float16)a.x; v[1] = (_Float16)a.y; v[2] = (_Float16)a.z; v[3] = (_Float16)a.w;
    v[4] = (_Float16)b.x; v[5] = (_Float16)b.y; v[6] = (_Float16)b.z; v[7] = (_Float16)b.w;
    *(half8*)(x16 + i) = v;
}

// ---------------------------------------------------------------------------
// Persistent recurrence. 256 wgs (1/CU) x 256 threads (4 waves).
// Tiling: wg = (rowgrp = wg>>6) x (colgrp = wg&63): 16 batch rows x 64 gemm
// cols (4 gates x 16 h-cols). Wave w = gate w.
// W_HH slice in dynamic LDS (132 KB). W_XH B-frags in registers (16 half8).
// h double-buffer inside d_out; h accessed ONLY via agent-scope relaxed
// atomics (write-through stores + LLC-direct b64 loads) -> NO fences, L2
// stays warm for x16/BN/weights across all 512 steps.
// Barrier: per-wg flag store + all-gather poll by each wg's wave 0.
// MODE 0: x16 in ws.  MODE 1: fp32 x (cvt in-loop).  MODE 2: cg::grid.sync.
// ---------------------------------------------------------------------------
template<int MODE>
__global__ __launch_bounds__(256, 1) void lstm_rec(
    const float* __restrict__ x, const float* __restrict__ w_xh,
    const float* __restrict__ w_hh, const float* __restrict__ bias,
    const float* __restrict__ scale, const float* __restrict__ offs,
    const float* __restrict__ pmean, const float* __restrict__ pvar,
    const _Float16* __restrict__ x16, int* flags, float* __restrict__ out)
{
    constexpr int KPH = HH + 8;  // f16 row stride 2064 B: +4 banks/row, <=2-way (free)
    extern __shared__ char smem[];
    _Float16* whh_l  = (_Float16*)smem;                   // 64*1032*2 = 132096 B
    float*    bias_l = (float*)(smem + 132096);           // 256 B
    float*    gbuf   = (float*)(smem + 132096 + 256);     // 64*17*4 = 4352 B

    const int wg  = blockIdx.x;
    const int tid = threadIdx.x;
    const int rowgrp = wg >> 6;          // 0..3  : batch rows [rowgrp*16, +16)
    const int colgrp = wg & 63;          // 0..63 : h-cols [colgrp*16, +16)
    const int lane = tid & 63, wid = tid >> 6;   // wid = gate index
    const int q = lane >> 4, r = lane & 15;

    // one-time: W_HH slice (64 gemm cols) -> LDS f16.  col(n) = (n>>4)*H + colgrp*16 + (n&15)
    for (int idx = tid; idx < 64 * HH; idx += 256) {
        int n = idx & 63, k = idx >> 6;
        int col = (n >> 4) * HH + colgrp * 16 + (n & 15);
        whh_l[n * KPH + k] = (_Float16)w_hh[(size_t)k * NG + col];
    }
    if (tid < 64) bias_l[tid] = bias[(tid >> 4) * HH + colgrp * 16 + (tid & 15)];

    // one-time: W_XH B-frags in registers. Wave wid covers gemm cols wid*H + colgrp*16 + r.
    half8 bx[16];
    {
        const int col = wid * HH + colgrp * 16 + r;
        #pragma unroll
        for (int kk = 0; kk < 16; ++kk)
            #pragma unroll
            for (int j = 0; j < 8; ++j)
                bx[kk][j] = (_Float16)w_xh[(size_t)(kk * 32 + q * 8 + j) * NG + col];
    }

    _Float16* hbuf = (_Float16*)out;     // buf0=[0,64K) buf1=[64K,128K) f16
    const int m_loc = tid >> 4, cl = tid & 15;   // epilogue ownership
    const int grow = rowgrp * 16 + m_loc;        // owned batch row
    const int hcol = colgrp * 16 + cl;           // owned h col
    if ((cl & 1) == 0)                            // zero h buf0, write-through
        __hip_atomic_store((unsigned*)(hbuf + grow * HH + hcol), 0u,
                           __ATOMIC_RELAXED, __HIP_MEMORY_SCOPE_AGENT);

    const int arow = rowgrp * 16 + r;    // A-frag batch row (same for all 4 waves)

    cg::grid_group grid = cg::this_grid();

    // step-0 BN params
    float bnmu  = pmean[hcol];
    float bniss = scale[hcol] * rsqrtf(pvar[hcol] + 1e-5f);
    float bnoff = offs[hcol];

    // x-GEMM: A from x16 (or fp32 x), B from bx registers. Independent of h.
    auto xgemm = [&](int t) -> f32x4 {
        f32x4 a4 = {0.0f, 0.0f, 0.0f, 0.0f};
        if constexpr (MODE == 0) {
            const _Float16* xr = x16 + ((size_t)arow * TT + t) * FF;
            #pragma unroll
            for (int kk = 0; kk < 16; ++kk) {
                half8 a = *(const half8*)(xr + kk * 32 + q * 8);
                a4 = __builtin_amdgcn_mfma_f32_16x16x32_f16(a, bx[kk], a4, 0, 0, 0);
            }
        } else {
            const float* xr = x + ((size_t)arow * TT + t) * FF;
            #pragma unroll
            for (int kk = 0; kk < 16; ++kk) {
                int kb = kk * 32 + q * 8;
                float4 x0 = *(const float4*)(xr + kb);
                float4 x1 = *(const float4*)(xr + kb + 4);
                half8 a;
                a[0] = (_Float16)x0.x; a[1] = (_Float16)x0.y;
                a[2] = (_Float16)x0.z; a[3] = (_Float16)x0.w;
                a[4] = (_Float16)x1.x; a[5] = (_Float16)x1.y;
                a[6] = (_Float16)x1.z; a[7] = (_Float16)x1.w;
                a4 = __builtin_amdgcn_mfma_f32_16x16x32_f16(a, bx[kk], a4, 0, 0, 0);
            }
        }
        return a4;
    };

    int ep = 1;
    __syncthreads();                      // per-wave vmcnt(0) drained (zeros at LLC)
    if constexpr (MODE == 2) { grid.sync(); }
    else if (tid == 0)
        __hip_atomic_store(&flags[wg], ep, __ATOMIC_RELAXED, __HIP_MEMORY_SCOPE_AGENT);

    f32x4 xacc = xgemm(0);

    if constexpr (MODE != 2) {
        if (tid < 64) {
            for (;;) {
                int ok = 1;
                #pragma unroll
                for (int j = 0; j < 4; ++j) {
                    int v = __hip_atomic_load(&flags[tid + 64 * j], __ATOMIC_RELAXED,
                                              __HIP_MEMORY_SCOPE_AGENT);
                    ok &= (v >= ep);
                }
                if (__all(ok)) break;
                __builtin_amdgcn_s_sleep(1);
            }
        }
        __syncthreads();
    }
    ++ep;

    float c_reg = 0.0f, h_out = 0.0f;
    int cur = 0;

    for (int t = 0; t < TT; ++t) {
        f32x4 acc = xacc;

        // h-GEMM: A = h rows [rowgrp*16,+16) via LLC-direct atomic b64 loads;
        // B = whh_l LDS. K = 1024 -> 32 MFMAs.
        const u64* hp = (const u64*)(hbuf + (size_t)cur * (BB * HH) + (size_t)arow * HH);
        #pragma unroll
        for (int kk = 0; kk < 32; ++kk) {
            u64 lo = __hip_atomic_load(hp + kk * 8 + q * 2, __ATOMIC_RELAXED,
                                       __HIP_MEMORY_SCOPE_AGENT);
            u64 hi = __hip_atomic_load(hp + kk * 8 + q * 2 + 1, __ATOMIC_RELAXED,
                                       __HIP_MEMORY_SCOPE_AGENT);
            union { u64 u[2]; half8 h; } cv;
            cv.u[0] = lo; cv.u[1] = hi;
            half8 b = *(const half8*)&whh_l[(wid * 16 + r) * KPH + kk * 32 + q * 8];
            acc = __builtin_amdgcn_mfma_f32_16x16x32_f16(cv.h, b, acc, 0, 0, 0);
        }

        // C layout: col = r, row = q*4+reg. Wave wid -> gate wid rows of gbuf.
        #pragma unroll
        for (int reg = 0; reg < 4; ++reg)
            gbuf[(wid * 16 + q * 4 + reg) * 17 + r] = acc[reg];
        __syncthreads();

        // cell update: thread (m_loc, cl) owns (grow, hcol)
        float f_ = gbuf[( 0 + m_loc) * 17 + cl] + bias_l[ 0 + cl];
        float i_ = gbuf[(16 + m_loc) * 17 + cl] + bias_l[16 + cl];
        float o_ = gbuf[(32 + m_loc) * 17 + cl] + bias_l[32 + cl];
        float g_ = gbuf[(48 + m_loc) * 17 + cl] + bias_l[48 + cl];
        c_reg = sigm(f_ + 1.0f) * c_reg + sigm(i_) * tanh_fast(g_);
        float cn = (c_reg - bnmu) * bniss + bnoff;
        h_out = sigm(o_) * tanh_fast(cn);

        // pack f16 pair across cl^1 and write-through to LLC (4-B atomic)
        {
            unsigned short hb = __builtin_bit_cast(unsigned short, (_Float16)h_out);
            unsigned short pb = (unsigned short)__shfl_xor((int)hb, 1, 64);
            if ((cl & 1) == 0) {
                unsigned packed = (unsigned)hb | ((unsigned)pb << 16);
                __hip_atomic_store(
                    (unsigned*)(hbuf + (size_t)(cur ^ 1) * (BB * HH) + grow * HH + hcol),
                    packed, __ATOMIC_RELAXED, __HIP_MEMORY_SCOPE_AGENT);
            }
        }

        // prefetch next BN params (h-independent, L2-warm)
        if (t + 1 < TT) {
            bnmu  = pmean[(t + 1) * HH + hcol];
            bniss = scale[(t + 1) * HH + hcol] * rsqrtf(pvar[(t + 1) * HH + hcol] + 1e-5f);
            bnoff = offs [(t + 1) * HH + hcol];
        }

        __syncthreads();   // every wave drains vmcnt (h stores at LLC); gbuf reads done
        if constexpr (MODE == 2) {
            if (t + 1 < TT) xacc = xgemm(t + 1);
            grid.sync();
        } else {
            if (tid == 0)
                __hip_atomic_store(&flags[wg], ep, __ATOMIC_RELAXED, __HIP_MEMORY_SCOPE_AGENT);
            if (t + 1 < TT) xacc = xgemm(t + 1);   // hidden under barrier wait
            if (tid < 64) {
                for (;;) {
                    int ok = 1;
                    #pragma unroll
                    for (int j = 0; j < 4; ++j) {
                        int v = __hip_atomic_load(&flags[tid + 64 * j], __ATOMIC_RELAXED,
                                                  __HIP_MEMORY_SCOPE_AGENT);
                        ok &= (v >= ep);
                    }
                    if (__all(ok)) break;
                    __builtin_amdgcn_s_sleep(1);
                }
            }
            __syncthreads();
        }
        ++ep;
        cur ^= 1;
    }

    // after final barrier nobody reads hbuf -> overwrite with fp32 output
    out[grow * HH + hcol] = h_out;
}

extern "C" void kernel_launch(void* const* d_in, const int* in_sizes, int n_in,
                              void* d_out, int out_size, void* d_ws, size_t ws_size,
                              hipStream_t stream) {
    const float* x     = (const float*)d_in[0];
    const float* w_xh  = (const float*)d_in[1];
    const float* w_hh  = (const float*)d_in[2];
    const float* bias  = (const float*)d_in[3];
    const float* scale = (const float*)d_in[4];
    const float* offs  = (const float*)d_in[5];
    const float* pmean = (const float*)d_in[6];
    const float* pvar  = (const float*)d_in[7];
    float* out = (float*)d_out;

    int* flags = (int*)d_ws;                          // 1 KB
    _Float16* x16 = (_Float16*)((char*)d_ws + 4096);  // 32 MiB
    const size_t X16B = (size_t)BB * TT * FF * 2;
    const int mode = (ws_size >= X16B + 4096) ? 0 : (ws_size >= 2048 ? 1 : 2);

    if (mode <= 1) (void)hipMemsetAsync(d_ws, 0, 2048, stream);
    if (mode == 0) {
        const size_t nelem = (size_t)BB * TT * FF;
        cvt_x<<<dim3((unsigned)(nelem / (256 * 8))), 256, 0, stream>>>(x, x16);
    }

    const uint32_t shmem = 132096 + 256 + 4352;   // 136704 B
    const void* f = (mode == 0) ? (const void*)&lstm_rec<0>
                  : (mode == 1) ? (const void*)&lstm_rec<1>
                                : (const void*)&lstm_rec<2>;
    (void)hipFuncSetAttribute(f, hipFuncAttributeMaxDynamicSharedMemorySize, (int)shmem);

    void* args[] = {&x, &w_xh, &w_hh, &bias, &scale, &offs, &pmean, &pvar,
                    &x16, &flags, &out};
    (void)hipLaunchCooperativeKernel(f, dim3(256), dim3(256), args, shmem, stream);
}